// Round 5
// baseline (370.094 us; speedup 1.0000x reference)
//
#include <hip/hip_runtime.h>
#include <hip/hip_bf16.h>
#include <stdint.h>

typedef uint16_t u16;
typedef __attribute__((ext_vector_type(8))) short bf16x8;
typedef __attribute__((ext_vector_type(4))) float f32x4;

#define DEVI static __device__ __forceinline__
#define GLOAD_LDS(gptr, lptr) \
  __builtin_amdgcn_global_load_lds((const __attribute__((address_space(1))) void*)(gptr), \
                                   (__attribute__((address_space(3))) void*)(lptr), 16, 0, 0)

constexpr int Bc = 4, Sc = 1024, Hc = 1024, NHc = 16, HDc = 64;
constexpr int Mrows = Bc * Sc; // 4096

DEVI u16 f2bf(float f) {
  uint32_t u = __builtin_bit_cast(uint32_t, f);
  u += 0x7FFFu + ((u >> 16) & 1u);
  return (u16)(u >> 16);
}
DEVI float bf2f(u16 x) { return __builtin_bit_cast(float, (uint32_t)x << 16); }

DEVI f32x4 mfma16(bf16x8 a, bf16x8 b, f32x4 c) {
  return __builtin_amdgcn_mfma_f32_16x16x32_bf16(a, b, c, 0, 0, 0);
}

// ---------------- f32 -> bf16 conversion ----------------
__global__ __launch_bounds__(256) void cvt_kernel(const float* __restrict__ in,
                                                  u16* __restrict__ out, int n8) {
  int i = blockIdx.x * 256 + threadIdx.x;
  if (i >= n8) return;
  const f32x4* p = (const f32x4*)(in + (size_t)i * 8);
  f32x4 a = p[0], b = p[1];
  union { bf16x8 v; u16 s[8]; } r;
#pragma unroll
  for (int j = 0; j < 4; ++j) { r.s[j] = f2bf(a[j]); r.s[4 + j] = f2bf(b[j]); }
  *(bf16x8*)(out + (size_t)i * 8) = r.v;
}

// ---------------- mask int32 -> bitmask ----------------
__global__ __launch_bounds__(256) void maskpack_kernel(const int* __restrict__ mask,
                                                       uint32_t* __restrict__ out) {
  int i = blockIdx.x * 256 + threadIdx.x;
  const int4* p = (const int4*)(mask + (size_t)i * 32);
  uint32_t r = 0;
#pragma unroll
  for (int j = 0; j < 8; ++j) {
    int4 v = p[j];
    uint32_t nib = (v.x ? 1u : 0u) | (v.y ? 2u : 0u) | (v.z ? 4u : 0u) | (v.w ? 8u : 0u);
    r |= nib << (j * 4);
  }
  out[i] = r;
}

// ---------------- fused 5-way projection GEMM ----------------
struct P5 { const u16* A[5]; const u16* W[5]; const float* b[5]; u16* o[5]; };

__global__ __launch_bounds__(256) void proj5_kernel(P5 args) {
  constexpr int K = 1024, BK = 32;
  __shared__ u16 As[128 * BK];
  __shared__ u16 Bs[128 * BK];
  const int z = blockIdx.z;
  const u16* __restrict__ A = args.A[z];
  const u16* __restrict__ Bw = args.W[z];
  const float* __restrict__ bias = args.b[z];
  u16* __restrict__ Cout = args.o[z];
  const int t = threadIdx.x;
  const int w = t >> 6, l = t & 63;
  const int lr = l & 15, lh = l >> 4;
  const int m0 = blockIdx.y * 128, n0 = blockIdx.x * 128;
  const int wr = w >> 1, wc = w & 1;
  f32x4 acc[4][4] = {};

  const int row_s = t >> 2, k8 = (t & 3) << 3;
  const u16* ga = A + (size_t)(m0 + row_s) * K + k8;
  const u16* gb = Bw + (size_t)(n0 + row_s) * K + k8;

  for (int kt = 0; kt < K; kt += BK) {
    GLOAD_LDS(ga + kt, As + t * 8);
    GLOAD_LDS(ga + (size_t)64 * K + kt, As + 2048 + t * 8);
    GLOAD_LDS(gb + kt, Bs + t * 8);
    GLOAD_LDS(gb + (size_t)64 * K + kt, Bs + 2048 + t * 8);
    __syncthreads();
    bf16x8 af[4], bfr[4];
#pragma unroll
    for (int mi = 0; mi < 4; ++mi)
      af[mi] = *(const bf16x8*)(As + (wr * 64 + mi * 16 + lr) * BK + lh * 8);
#pragma unroll
    for (int ni = 0; ni < 4; ++ni)
      bfr[ni] = *(const bf16x8*)(Bs + (wc * 64 + ni * 16 + lr) * BK + lh * 8);
#pragma unroll
    for (int mi = 0; mi < 4; ++mi)
#pragma unroll
      for (int ni = 0; ni < 4; ++ni)
        acc[mi][ni] = mfma16(af[mi], bfr[ni], acc[mi][ni]);
    __syncthreads();
  }

#pragma unroll
  for (int mi = 0; mi < 4; ++mi) {
#pragma unroll
    for (int ni = 0; ni < 4; ++ni) {
      int col = n0 + wc * 64 + ni * 16 + lr;
      float bc = bias[col];
      int hcol = col >> 6, dcol = col & 63;
      int rbase = m0 + wr * 64 + mi * 16 + lh * 4;
      int bb = rbase >> 10, sb = rbase & 1023;
      if (z == 4) {
        ushort4 pk;
        pk.x = f2bf(acc[mi][ni][0] + bc);
        pk.y = f2bf(acc[mi][ni][1] + bc);
        pk.z = f2bf(acc[mi][ni][2] + bc);
        pk.w = f2bf(acc[mi][ni][3] + bc);
        *(ushort4*)&Cout[((size_t)(bb * NHc + hcol) * HDc + dcol) * Sc + sb] = pk;
      } else {
#pragma unroll
        for (int r = 0; r < 4; ++r)
          Cout[((size_t)(bb * NHc + hcol) * Sc + (sb + r)) * HDc + dcol] =
              f2bf(acc[mi][ni][r] + bc);
      }
    }
  }
}

// ---------------- output projection GEMM (f32 out, [M,N]) ----------------
__global__ __launch_bounds__(256) void gemmo_kernel(const u16* __restrict__ A,
                                                    const u16* __restrict__ Bw,
                                                    const float* __restrict__ bias,
                                                    float* __restrict__ Cout) {
  constexpr int K = 1024, N = 1024, BK = 32;
  __shared__ u16 As[128 * BK];
  __shared__ u16 Bs[128 * BK];
  const int t = threadIdx.x;
  const int w = t >> 6, l = t & 63;
  const int lr = l & 15, lh = l >> 4;
  const int m0 = blockIdx.y * 128, n0 = blockIdx.x * 128;
  const int wr = w >> 1, wc = w & 1;
  f32x4 acc[4][4] = {};

  const int row_s = t >> 2, k8 = (t & 3) << 3;
  const u16* ga = A + (size_t)(m0 + row_s) * K + k8;
  const u16* gb = Bw + (size_t)(n0 + row_s) * K + k8;

  for (int kt = 0; kt < K; kt += BK) {
    GLOAD_LDS(ga + kt, As + t * 8);
    GLOAD_LDS(ga + (size_t)64 * K + kt, As + 2048 + t * 8);
    GLOAD_LDS(gb + kt, Bs + t * 8);
    GLOAD_LDS(gb + (size_t)64 * K + kt, Bs + 2048 + t * 8);
    __syncthreads();
    bf16x8 af[4], bfr[4];
#pragma unroll
    for (int mi = 0; mi < 4; ++mi)
      af[mi] = *(const bf16x8*)(As + (wr * 64 + mi * 16 + lr) * BK + lh * 8);
#pragma unroll
    for (int ni = 0; ni < 4; ++ni)
      bfr[ni] = *(const bf16x8*)(Bs + (wc * 64 + ni * 16 + lr) * BK + lh * 8);
#pragma unroll
    for (int mi = 0; mi < 4; ++mi)
#pragma unroll
      for (int ni = 0; ni < 4; ++ni)
        acc[mi][ni] = mfma16(af[mi], bfr[ni], acc[mi][ni]);
    __syncthreads();
  }

#pragma unroll
  for (int mi = 0; mi < 4; ++mi) {
#pragma unroll
    for (int ni = 0; ni < 4; ++ni) {
      int col = n0 + wc * 64 + ni * 16 + lr;
      float bc = bias[col];
#pragma unroll
      for (int r = 0; r < 4; ++r) {
        int rowg = m0 + wr * 64 + mi * 16 + lh * 4 + r;
        Cout[(size_t)rowg * N + col] = acc[mi][ni][r] + bc;
      }
    }
  }
}

// ---------------- fused attention: energy + select + softmax + PV ------------
// E in LDS as bf16 [16][1024], swizzled at 16B granularity:
//   u16 index(row,k) = row*1024 + (((k>>3) ^ (row&7)) << 3) | (k&7)
// Energy uses SWAPPED mfma (A=K, B=Q): C col=lane&15 -> q, row=lh*4+r -> k,
// so each lane holds 4 consecutive k for one q-row => 1 dword mask + 1 ushort4 store.
__global__ __launch_bounds__(256, 3) void attn_kernel(const u16* __restrict__ Qh,
                                                      const u16* __restrict__ Kh,
                                                      const u16* __restrict__ Qsh,
                                                      const u16* __restrict__ Ksh,
                                                      const u16* __restrict__ Vth,
                                                      const uint32_t* __restrict__ mbits,
                                                      float* __restrict__ Pout,
                                                      u16* __restrict__ ctx) {
  __shared__ __align__(16) u16 E[16 * 1024]; // 32 KB
  const int t = threadIdx.x, w = t >> 6, l = t & 63;
  const int lr = l & 15, lh = l >> 4;
  // XCD-aware remap: 64 q-tiles of one head stay on one XCD
  int lid = blockIdx.y * 64 + blockIdx.x;
  int xcd = lid & 7, j = lid >> 3;
  int bh = xcd * 8 + (j >> 6);
  int q0 = (j & 63) << 4;
  const int b = bh >> 4, h = bh & 15;
  const size_t hoff = (size_t)bh * Sc * HDc;

  // ---- energy: wave w covers k in [w*256, w*256+256) ----
  const u16* Qp = Qh + hoff + (size_t)(q0 + lr) * HDc + lh * 8;
  const u16* Qsp = Qsh + hoff + (size_t)(q0 + lr) * HDc + lh * 8;
  bf16x8 qf0 = *(const bf16x8*)Qp, qf1 = *(const bf16x8*)(Qp + 32);
  bf16x8 sf0 = *(const bf16x8*)Qsp, sf1 = *(const bf16x8*)(Qsp + 32);

  const u16* Kbase = Kh + hoff + (size_t)((w << 8) + lr) * HDc + lh * 8;
  const u16* Ksbase = Ksh + hoff + (size_t)((w << 8) + lr) * HDc + lh * 8;
  // this lane's q-row mask words for col window [w*256, (w+1)*256)
  const uint32_t* mrow_l = mbits + ((size_t)b * Sc + q0 + lr) * 32 + w * 8;

#pragma unroll
  for (int kt = 0; kt < 16; ++kt) {
    const u16* Kp = Kbase + kt * (16 * HDc);
    const u16* Ksp = Ksbase + kt * (16 * HDc);
    f32x4 e = {}, es = {};
    e = mfma16(*(const bf16x8*)Kp, qf0, e);
    e = mfma16(*(const bf16x8*)(Kp + 32), qf1, e);
    es = mfma16(*(const bf16x8*)Ksp, sf0, es);
    es = mfma16(*(const bf16x8*)(Ksp + 32), sf1, es);
    uint32_t md = mrow_l[kt >> 1];
    int sh = ((kt & 1) << 4) + (lh << 2);
    ushort4 wb;
    wb.x = f2bf(((md >> (sh + 0)) & 1u ? es[0] : e[0]) * 0.125f);
    wb.y = f2bf(((md >> (sh + 1)) & 1u ? es[1] : e[1]) * 0.125f);
    wb.z = f2bf(((md >> (sh + 2)) & 1u ? es[2] : e[2]) * 0.125f);
    wb.w = f2bf(((md >> (sh + 3)) & 1u ? es[3] : e[3]) * 0.125f);
    int kb = (w << 8) + (kt << 4) + (lh << 2); // base k of this lane's 4 values
    int kg = kb >> 3;
    *(ushort4*)&E[(lr << 10) + (((kg ^ (lr & 7)) << 3) | (kb & 7))] = wb;
  }
  __syncthreads();

  // ---- softmax: wave w handles rows w*4 .. w*4+3; lane owns k=j*256+l*4 ----
  float* Pbase = Pout + ((size_t)bh * Sc + q0) * Sc;
#pragma unroll
  for (int rr = 0; rr < 4; ++rr) {
    int row = (w << 2) + rr;
    int sw = row & 7;
    float v[4][4];
#pragma unroll
    for (int jj = 0; jj < 4; ++jj) {
      int k = jj * 256 + (l << 2);
      ushort4 raw = *(const ushort4*)&E[(row << 10) + ((((k >> 3) ^ sw) << 3) | (k & 7))];
      v[jj][0] = bf2f(raw.x); v[jj][1] = bf2f(raw.y);
      v[jj][2] = bf2f(raw.z); v[jj][3] = bf2f(raw.w);
    }
    float m = -1e30f;
#pragma unroll
    for (int jj = 0; jj < 4; ++jj)
      m = fmaxf(m, fmaxf(fmaxf(v[jj][0], v[jj][1]), fmaxf(v[jj][2], v[jj][3])));
#pragma unroll
    for (int off = 32; off; off >>= 1) m = fmaxf(m, __shfl_xor(m, off));
    float s = 0.f;
#pragma unroll
    for (int jj = 0; jj < 4; ++jj)
#pragma unroll
      for (int i = 0; i < 4; ++i) { float tt = __expf(v[jj][i] - m); v[jj][i] = tt; s += tt; }
#pragma unroll
    for (int off = 32; off; off >>= 1) s += __shfl_xor(s, off);
    float inv = 1.f / s;
#pragma unroll
    for (int jj = 0; jj < 4; ++jj) {
      int k = jj * 256 + (l << 2);
      f32x4 pv = { v[jj][0] * inv, v[jj][1] * inv, v[jj][2] * inv, v[jj][3] * inv };
      *(f32x4*)(Pbase + (size_t)row * Sc + k) = pv;
      ushort4 wb;
      wb.x = f2bf(pv[0]); wb.y = f2bf(pv[1]); wb.z = f2bf(pv[2]); wb.w = f2bf(pv[3]);
      *(ushort4*)&E[(row << 10) + ((((k >> 3) ^ sw) << 3) | (k & 7))] = wb;
    }
  }
  __syncthreads();

  // ---- PV: wave w handles d-cols [w*16, w*16+16); A-frags straight from LDS ----
  const u16* Vb = Vth + ((size_t)bh * HDc + (w << 4) + lr) * Sc + lh * 8;
  const int swp = lr & 7;
  f32x4 acc0 = {}, acc1 = {};
#pragma unroll
  for (int k0 = 0; k0 < 1024; k0 += 64) {
    int ka = k0 + (lh << 3);
    bf16x8 a0 = *(const bf16x8*)&E[(lr << 10) + (((ka >> 3) ^ swp) << 3)];
    bf16x8 b0 = *(const bf16x8*)(Vb + k0);
    acc0 = mfma16(a0, b0, acc0);
    int kb = ka + 32;
    bf16x8 a1 = *(const bf16x8*)&E[(lr << 10) + (((kb >> 3) ^ swp) << 3)];
    bf16x8 b1 = *(const bf16x8*)(Vb + k0 + 32);
    acc1 = mfma16(a1, b1, acc1);
  }
  f32x4 acc = acc0 + acc1;
#pragma unroll
  for (int r = 0; r < 4; ++r) {
    int row = q0 + (lh << 2) + r;
    ctx[((size_t)b * Sc + row) * Hc + (h << 6) + (w << 4) + lr] = f2bf(acc[r]);
  }
}

extern "C" void kernel_launch(void* const* d_in, const int* in_sizes, int n_in,
                              void* d_out, int out_size, void* d_ws, size_t ws_size,
                              hipStream_t stream) {
  const float* fin[5] = { (const float*)d_in[0], (const float*)d_in[1], (const float*)d_in[2],
                          (const float*)d_in[3], (const float*)d_in[4] };
  const int* mask = (const int*)d_in[5];
  const float* W[6] = { (const float*)d_in[6], (const float*)d_in[8], (const float*)d_in[10],
                        (const float*)d_in[12], (const float*)d_in[14], (const float*)d_in[16] };
  const float* bias[6] = { (const float*)d_in[7], (const float*)d_in[9], (const float*)d_in[11],
                           (const float*)d_in[13], (const float*)d_in[15], (const float*)d_in[17] };

  float* out_x = (float*)d_out;
  float* out_attn = out_x + (size_t)Bc * Sc * Hc;

  const size_t NE = (size_t)Bc * Sc * Hc; // 4M elems
  const size_t NW = (size_t)Hc * Hc;      // 1M elems
  u16* p = (u16*)d_ws;
  u16* xin[5]; for (int i = 0; i < 5; ++i) { xin[i] = p; p += NE; }
  u16* wbf[6]; for (int i = 0; i < 6; ++i) { wbf[i] = p; p += NW; }
  u16* Qh  = p; p += NE;
  u16* Kh  = p; p += NE;
  u16* Qsh = p; p += NE;
  u16* Ksh = p; p += NE;
  u16* Vth = p; p += NE;
  u16* ctx = p; p += NE;
  uint32_t* mbits = (uint32_t*)xin[0]; // reused after proj5

  for (int i = 0; i < 5; ++i)
    cvt_kernel<<<(int)(NE / 8 / 256), 256, 0, stream>>>(fin[i], xin[i], (int)(NE / 8));
  for (int i = 0; i < 6; ++i)
    cvt_kernel<<<(int)(NW / 8 / 256), 256, 0, stream>>>(W[i], wbf[i], (int)(NW / 8));

  P5 args;
  u16* projout[5] = { Qh, Kh, Qsh, Ksh, Vth };
  for (int i = 0; i < 5; ++i) { args.A[i] = xin[i]; args.W[i] = wbf[i]; args.b[i] = bias[i]; args.o[i] = projout[i]; }
  proj5_kernel<<<dim3(Hc / 128, Mrows / 128, 5), 256, 0, stream>>>(args);

  maskpack_kernel<<<(int)((size_t)Bc * Sc * Sc / 32 / 256), 256, 0, stream>>>(mask, mbits);

  attn_kernel<<<dim3(Sc / 16, Bc * NHc), 256, 0, stream>>>(Qh, Kh, Qsh, Ksh, Vth, mbits, out_attn, ctx);

  gemmo_kernel<<<dim3(Hc / 128, Mrows / 128), 256, 0, stream>>>(ctx, wbf[5], bias[5], out_x);
}

// Round 6
// 330.036 us; speedup vs baseline: 1.1214x; 1.1214x over previous
//
#include <hip/hip_runtime.h>
#include <hip/hip_bf16.h>
#include <stdint.h>

typedef uint16_t u16;
typedef __attribute__((ext_vector_type(8))) short bf16x8;
typedef __attribute__((ext_vector_type(4))) float f32x4;

#define DEVI static __device__ __forceinline__
#define GLOAD_LDS(gptr, lptr) \
  __builtin_amdgcn_global_load_lds((const __attribute__((address_space(1))) void*)(gptr), \
                                   (__attribute__((address_space(3))) void*)(lptr), 16, 0, 0)

constexpr int Bc = 4, Sc = 1024, Hc = 1024, NHc = 16, HDc = 64;
constexpr int Mrows = Bc * Sc; // 4096

DEVI u16 f2bf(float f) {
  uint32_t u = __builtin_bit_cast(uint32_t, f);
  u += 0x7FFFu + ((u >> 16) & 1u);
  return (u16)(u >> 16);
}
DEVI float bf2f(u16 x) { return __builtin_bit_cast(float, (uint32_t)x << 16); }

DEVI f32x4 mfma16(bf16x8 a, bf16x8 b, f32x4 c) {
  return __builtin_amdgcn_mfma_f32_16x16x32_bf16(a, b, c, 0, 0, 0);
}

// ---------------- batched f32 -> bf16 conversion ----------------
struct CV { const float* in[6]; u16* out[6]; };

__global__ __launch_bounds__(256) void cvtN_kernel(CV a, int n8) {
  int z = blockIdx.z;
  int i = blockIdx.x * 256 + threadIdx.x;
  if (i >= n8) return;
  const f32x4* p = (const f32x4*)(a.in[z] + (size_t)i * 8);
  f32x4 x = p[0], y = p[1];
  union { bf16x8 v; u16 s[8]; } r;
#pragma unroll
  for (int j = 0; j < 4; ++j) { r.s[j] = f2bf(x[j]); r.s[4 + j] = f2bf(y[j]); }
  *(bf16x8*)(a.out[z] + (size_t)i * 8) = r.v;
}

// ---------------- mask int32 -> bitmask ----------------
__global__ __launch_bounds__(256) void maskpack_kernel(const int* __restrict__ mask,
                                                       uint32_t* __restrict__ out) {
  int i = blockIdx.x * 256 + threadIdx.x;
  const int4* p = (const int4*)(mask + (size_t)i * 32);
  uint32_t r = 0;
#pragma unroll
  for (int j = 0; j < 8; ++j) {
    int4 v = p[j];
    uint32_t nib = (v.x ? 1u : 0u) | (v.y ? 2u : 0u) | (v.z ? 4u : 0u) | (v.w ? 8u : 0u);
    r |= nib << (j * 4);
  }
  out[i] = r;
}

// ---------------- fused 5-way projection GEMM ----------------
struct P5 { const u16* A[5]; const u16* W[5]; const float* b[5]; u16* o[5]; };

__global__ __launch_bounds__(256) void proj5_kernel(P5 args) {
  constexpr int K = 1024, BK = 32;
  __shared__ u16 As[128 * BK];
  __shared__ u16 Bs[128 * BK];
  const int z = blockIdx.z;
  const u16* __restrict__ A = args.A[z];
  const u16* __restrict__ Bw = args.W[z];
  const float* __restrict__ bias = args.b[z];
  u16* __restrict__ Cout = args.o[z];
  const int t = threadIdx.x;
  const int w = t >> 6, l = t & 63;
  const int lr = l & 15, lh = l >> 4;
  const int m0 = blockIdx.y * 128, n0 = blockIdx.x * 128;
  const int wr = w >> 1, wc = w & 1;
  f32x4 acc[4][4] = {};

  const int row_s = t >> 2, k8 = (t & 3) << 3;
  const u16* ga = A + (size_t)(m0 + row_s) * K + k8;
  const u16* gb = Bw + (size_t)(n0 + row_s) * K + k8;

  for (int kt = 0; kt < K; kt += BK) {
    GLOAD_LDS(ga + kt, As + t * 8);
    GLOAD_LDS(ga + (size_t)64 * K + kt, As + 2048 + t * 8);
    GLOAD_LDS(gb + kt, Bs + t * 8);
    GLOAD_LDS(gb + (size_t)64 * K + kt, Bs + 2048 + t * 8);
    __syncthreads();
    bf16x8 af[4], bfr[4];
#pragma unroll
    for (int mi = 0; mi < 4; ++mi)
      af[mi] = *(const bf16x8*)(As + (wr * 64 + mi * 16 + lr) * BK + lh * 8);
#pragma unroll
    for (int ni = 0; ni < 4; ++ni)
      bfr[ni] = *(const bf16x8*)(Bs + (wc * 64 + ni * 16 + lr) * BK + lh * 8);
#pragma unroll
    for (int mi = 0; mi < 4; ++mi)
#pragma unroll
      for (int ni = 0; ni < 4; ++ni)
        acc[mi][ni] = mfma16(af[mi], bfr[ni], acc[mi][ni]);
    __syncthreads();
  }

#pragma unroll
  for (int mi = 0; mi < 4; ++mi) {
#pragma unroll
    for (int ni = 0; ni < 4; ++ni) {
      int col = n0 + wc * 64 + ni * 16 + lr;
      float bc = bias[col];
      int hcol = col >> 6, dcol = col & 63;
      int rbase = m0 + wr * 64 + mi * 16 + lh * 4;
      int bb = rbase >> 10, sb = rbase & 1023;
      if (z == 4) {
        ushort4 pk;
        pk.x = f2bf(acc[mi][ni][0] + bc);
        pk.y = f2bf(acc[mi][ni][1] + bc);
        pk.z = f2bf(acc[mi][ni][2] + bc);
        pk.w = f2bf(acc[mi][ni][3] + bc);
        *(ushort4*)&Cout[((size_t)(bb * NHc + hcol) * HDc + dcol) * Sc + sb] = pk;
      } else {
#pragma unroll
        for (int r = 0; r < 4; ++r)
          Cout[((size_t)(bb * NHc + hcol) * Sc + (sb + r)) * HDc + dcol] =
              f2bf(acc[mi][ni][r] + bc);
      }
    }
  }
}

// ---------------- output projection GEMM (f32 out, [M,N]) ----------------
__global__ __launch_bounds__(256) void gemmo_kernel(const u16* __restrict__ A,
                                                    const u16* __restrict__ Bw,
                                                    const float* __restrict__ bias,
                                                    float* __restrict__ Cout) {
  constexpr int K = 1024, N = 1024, BK = 32;
  __shared__ u16 As[128 * BK];
  __shared__ u16 Bs[128 * BK];
  const int t = threadIdx.x;
  const int w = t >> 6, l = t & 63;
  const int lr = l & 15, lh = l >> 4;
  const int m0 = blockIdx.y * 128, n0 = blockIdx.x * 128;
  const int wr = w >> 1, wc = w & 1;
  f32x4 acc[4][4] = {};

  const int row_s = t >> 2, k8 = (t & 3) << 3;
  const u16* ga = A + (size_t)(m0 + row_s) * K + k8;
  const u16* gb = Bw + (size_t)(n0 + row_s) * K + k8;

  for (int kt = 0; kt < K; kt += BK) {
    GLOAD_LDS(ga + kt, As + t * 8);
    GLOAD_LDS(ga + (size_t)64 * K + kt, As + 2048 + t * 8);
    GLOAD_LDS(gb + kt, Bs + t * 8);
    GLOAD_LDS(gb + (size_t)64 * K + kt, Bs + 2048 + t * 8);
    __syncthreads();
    bf16x8 af[4], bfr[4];
#pragma unroll
    for (int mi = 0; mi < 4; ++mi)
      af[mi] = *(const bf16x8*)(As + (wr * 64 + mi * 16 + lr) * BK + lh * 8);
#pragma unroll
    for (int ni = 0; ni < 4; ++ni)
      bfr[ni] = *(const bf16x8*)(Bs + (wc * 64 + ni * 16 + lr) * BK + lh * 8);
#pragma unroll
    for (int mi = 0; mi < 4; ++mi)
#pragma unroll
      for (int ni = 0; ni < 4; ++ni)
        acc[mi][ni] = mfma16(af[mi], bfr[ni], acc[mi][ni]);
    __syncthreads();
  }

#pragma unroll
  for (int mi = 0; mi < 4; ++mi) {
#pragma unroll
    for (int ni = 0; ni < 4; ++ni) {
      int col = n0 + wc * 64 + ni * 16 + lr;
      float bc = bias[col];
#pragma unroll
      for (int r = 0; r < 4; ++r) {
        int rowg = m0 + wr * 64 + mi * 16 + lh * 4 + r;
        Cout[(size_t)rowg * N + col] = acc[mi][ni][r] + bc;
      }
    }
  }
}

// ---------------- fused attention: energy + select + softmax + PV ------------
// E in LDS as bf16 [16][1024], swizzled at 16B granularity:
//   u16 index(row,k) = row*1024 + (((k>>3) ^ (row&7)) << 3) | (k&7)
// Energy uses SWAPPED mfma (A=K, B=Q): lane holds 4 consecutive k for one q-row.
// P stores are NON-TEMPORAL: P is write-once; keep the 268MB stream out of L2
// so K/Ks/V stay L2-resident.
__global__ __launch_bounds__(256, 3) void attn_kernel(const u16* __restrict__ Qh,
                                                      const u16* __restrict__ Kh,
                                                      const u16* __restrict__ Qsh,
                                                      const u16* __restrict__ Ksh,
                                                      const u16* __restrict__ Vth,
                                                      const uint32_t* __restrict__ mbits,
                                                      float* __restrict__ Pout,
                                                      u16* __restrict__ ctx) {
  __shared__ __align__(16) u16 E[16 * 1024]; // 32 KB
  const int t = threadIdx.x, w = t >> 6, l = t & 63;
  const int lr = l & 15, lh = l >> 4;
  // XCD-aware remap: 64 q-tiles of one head stay on one XCD
  int lid = blockIdx.y * 64 + blockIdx.x;
  int xcd = lid & 7, j = lid >> 3;
  int bh = xcd * 8 + (j >> 6);
  int q0 = (j & 63) << 4;
  const int b = bh >> 4, h = bh & 15;
  const size_t hoff = (size_t)bh * Sc * HDc;

  // ---- energy: wave w covers k in [w*256, w*256+256) ----
  const u16* Qp = Qh + hoff + (size_t)(q0 + lr) * HDc + lh * 8;
  const u16* Qsp = Qsh + hoff + (size_t)(q0 + lr) * HDc + lh * 8;
  bf16x8 qf0 = *(const bf16x8*)Qp, qf1 = *(const bf16x8*)(Qp + 32);
  bf16x8 sf0 = *(const bf16x8*)Qsp, sf1 = *(const bf16x8*)(Qsp + 32);

  const u16* Kbase = Kh + hoff + (size_t)((w << 8) + lr) * HDc + lh * 8;
  const u16* Ksbase = Ksh + hoff + (size_t)((w << 8) + lr) * HDc + lh * 8;
  const uint32_t* mrow_l = mbits + ((size_t)b * Sc + q0 + lr) * 32 + w * 8;

#pragma unroll
  for (int kt = 0; kt < 16; ++kt) {
    const u16* Kp = Kbase + kt * (16 * HDc);
    const u16* Ksp = Ksbase + kt * (16 * HDc);
    f32x4 e = {}, es = {};
    e = mfma16(*(const bf16x8*)Kp, qf0, e);
    e = mfma16(*(const bf16x8*)(Kp + 32), qf1, e);
    es = mfma16(*(const bf16x8*)Ksp, sf0, es);
    es = mfma16(*(const bf16x8*)(Ksp + 32), sf1, es);
    uint32_t md = mrow_l[kt >> 1];
    int sh = ((kt & 1) << 4) + (lh << 2);
    ushort4 wb;
    wb.x = f2bf(((md >> (sh + 0)) & 1u ? es[0] : e[0]) * 0.125f);
    wb.y = f2bf(((md >> (sh + 1)) & 1u ? es[1] : e[1]) * 0.125f);
    wb.z = f2bf(((md >> (sh + 2)) & 1u ? es[2] : e[2]) * 0.125f);
    wb.w = f2bf(((md >> (sh + 3)) & 1u ? es[3] : e[3]) * 0.125f);
    int kb = (w << 8) + (kt << 4) + (lh << 2);
    int kg = kb >> 3;
    *(ushort4*)&E[(lr << 10) + (((kg ^ (lr & 7)) << 3) | (kb & 7))] = wb;
  }
  __syncthreads();

  // ---- softmax: wave w handles rows w*4 .. w*4+3; lane owns k=j*256+l*4 ----
  float* Pbase = Pout + ((size_t)bh * Sc + q0) * Sc;
#pragma unroll
  for (int rr = 0; rr < 4; ++rr) {
    int row = (w << 2) + rr;
    int sw = row & 7;
    float v[4][4];
#pragma unroll
    for (int jj = 0; jj < 4; ++jj) {
      int k = jj * 256 + (l << 2);
      ushort4 raw = *(const ushort4*)&E[(row << 10) + ((((k >> 3) ^ sw) << 3) | (k & 7))];
      v[jj][0] = bf2f(raw.x); v[jj][1] = bf2f(raw.y);
      v[jj][2] = bf2f(raw.z); v[jj][3] = bf2f(raw.w);
    }
    float m = -1e30f;
#pragma unroll
    for (int jj = 0; jj < 4; ++jj)
      m = fmaxf(m, fmaxf(fmaxf(v[jj][0], v[jj][1]), fmaxf(v[jj][2], v[jj][3])));
#pragma unroll
    for (int off = 32; off; off >>= 1) m = fmaxf(m, __shfl_xor(m, off));
    float s = 0.f;
#pragma unroll
    for (int jj = 0; jj < 4; ++jj)
#pragma unroll
      for (int i = 0; i < 4; ++i) { float tt = __expf(v[jj][i] - m); v[jj][i] = tt; s += tt; }
#pragma unroll
    for (int off = 32; off; off >>= 1) s += __shfl_xor(s, off);
    float inv = 1.f / s;
#pragma unroll
    for (int jj = 0; jj < 4; ++jj) {
      int k = jj * 256 + (l << 2);
      f32x4 pv = { v[jj][0] * inv, v[jj][1] * inv, v[jj][2] * inv, v[jj][3] * inv };
      __builtin_nontemporal_store(pv, (f32x4*)(Pbase + (size_t)row * Sc + k));
      ushort4 wb;
      wb.x = f2bf(pv[0]); wb.y = f2bf(pv[1]); wb.z = f2bf(pv[2]); wb.w = f2bf(pv[3]);
      *(ushort4*)&E[(row << 10) + ((((k >> 3) ^ sw) << 3) | (k & 7))] = wb;
    }
  }
  __syncthreads();

  // ---- PV: wave w handles d-cols [w*16, w*16+16); A-frags straight from LDS ----
  const u16* Vb = Vth + ((size_t)bh * HDc + (w << 4) + lr) * Sc + lh * 8;
  const int swp = lr & 7;
  f32x4 acc0 = {}, acc1 = {};
#pragma unroll
  for (int k0 = 0; k0 < 1024; k0 += 64) {
    int ka = k0 + (lh << 3);
    bf16x8 a0 = *(const bf16x8*)&E[(lr << 10) + (((ka >> 3) ^ swp) << 3)];
    bf16x8 b0 = *(const bf16x8*)(Vb + k0);
    acc0 = mfma16(a0, b0, acc0);
    int kb = ka + 32;
    bf16x8 a1 = *(const bf16x8*)&E[(lr << 10) + (((kb >> 3) ^ swp) << 3)];
    bf16x8 b1 = *(const bf16x8*)(Vb + k0 + 32);
    acc1 = mfma16(a1, b1, acc1);
  }
  f32x4 acc = acc0 + acc1;
#pragma unroll
  for (int r = 0; r < 4; ++r) {
    int row = q0 + (lh << 2) + r;
    ctx[((size_t)b * Sc + row) * Hc + (h << 6) + (w << 4) + lr] = f2bf(acc[r]);
  }
}

extern "C" void kernel_launch(void* const* d_in, const int* in_sizes, int n_in,
                              void* d_out, int out_size, void* d_ws, size_t ws_size,
                              hipStream_t stream) {
  const float* fin[5] = { (const float*)d_in[0], (const float*)d_in[1], (const float*)d_in[2],
                          (const float*)d_in[3], (const float*)d_in[4] };
  const int* mask = (const int*)d_in[5];
  const float* W[6] = { (const float*)d_in[6], (const float*)d_in[8], (const float*)d_in[10],
                        (const float*)d_in[12], (const float*)d_in[14], (const float*)d_in[16] };
  const float* bias[6] = { (const float*)d_in[7], (const float*)d_in[9], (const float*)d_in[11],
                           (const float*)d_in[13], (const float*)d_in[15], (const float*)d_in[17] };

  float* out_x = (float*)d_out;
  float* out_attn = out_x + (size_t)Bc * Sc * Hc;

  const size_t NE = (size_t)Bc * Sc * Hc; // 4M elems
  const size_t NW = (size_t)Hc * Hc;      // 1M elems
  u16* p = (u16*)d_ws;
  u16* xin[5]; for (int i = 0; i < 5; ++i) { xin[i] = p; p += NE; }
  u16* wbf[6]; for (int i = 0; i < 6; ++i) { wbf[i] = p; p += NW; }
  u16* Qh  = p; p += NE;
  u16* Kh  = p; p += NE;
  u16* Qsh = p; p += NE;
  u16* Ksh = p; p += NE;
  u16* Vth = p; p += NE;
  u16* ctx = p; p += NE;
  uint32_t* mbits = (uint32_t*)xin[0]; // reused after proj5

  {
    CV a{};
    for (int i = 0; i < 5; ++i) { a.in[i] = fin[i]; a.out[i] = xin[i]; }
    cvtN_kernel<<<dim3((int)(NE / 8 / 256), 1, 5), 256, 0, stream>>>(a, (int)(NE / 8));
  }
  {
    CV a{};
    for (int i = 0; i < 6; ++i) { a.in[i] = W[i]; a.out[i] = wbf[i]; }
    cvtN_kernel<<<dim3((int)(NW / 8 / 256), 1, 6), 256, 0, stream>>>(a, (int)(NW / 8));
  }

  P5 args;
  u16* projout[5] = { Qh, Kh, Qsh, Ksh, Vth };
  for (int i = 0; i < 5; ++i) { args.A[i] = xin[i]; args.W[i] = wbf[i]; args.b[i] = bias[i]; args.o[i] = projout[i]; }
  proj5_kernel<<<dim3(Hc / 128, Mrows / 128, 5), 256, 0, stream>>>(args);

  maskpack_kernel<<<(int)((size_t)Bc * Sc * Sc / 32 / 256), 256, 0, stream>>>(mask, mbits);

  attn_kernel<<<dim3(Sc / 16, Bc * NHc), 256, 0, stream>>>(Qh, Kh, Qsh, Ksh, Vth, mbits, out_attn, ctx);

  gemmo_kernel<<<dim3(Hc / 128, Mrows / 128), 256, 0, stream>>>(ctx, wbf[5], bias[5], out_x);
}